// Round 4
// baseline (260.332 us; speedup 1.0000x reference)
//
#include <hip/hip_runtime.h>

#define NPIX    65536
#define D       64
#define KCODES  1024
#define SPLIT   4
#define KCHUNK  (KCODES / SPLIT)   // 256
#define PIXB    64
#define BLOCK   256

// d_out layout (floats):
//   [0]                  loss
//   [1 .. 4194305)       quantized_out (NCHW, 16x64x64x64)
//   [4194305]            perplexity
//   [4194306 .. 71303170) encodings (65536 x 1024)
//   [71303170 .. 71368706) indices (as float)
#define QUANT_OFF 1
#define PERP_OFF  4194305
#define ENC_OFF   4194306u
#define IDX_OFF   71303170u

// numpy pairwise_sum (8 <= n <= 128) for n=64: 8 accumulators over stride-8
// lanes, sequential adds, then ((r0+r1)+(r2+r3))+((r4+r5)+(r6+r7)).
// All ops via __fmul_rn/__fadd_rn so the compiler cannot contract or reorder.

__global__ __launch_bounds__(256) void vq_init(const float* __restrict__ emb,
                                               double* __restrict__ loss_sum,
                                               int* __restrict__ counts,
                                               float* __restrict__ se) {
    int t = blockIdx.x * 256 + threadIdx.x;
    if (t == 0) *loss_sum = 0.0;
    if (t < KCODES) {
        counts[t] = 0;
        const float* e = emb + (size_t)t * D;
        float r[8];
        #pragma unroll
        for (int j = 0; j < 8; ++j) r[j] = __fmul_rn(e[j], e[j]);
        #pragma unroll
        for (int i = 8; i < D; i += 8)
            #pragma unroll
            for (int j = 0; j < 8; ++j)
                r[j] = __fadd_rn(r[j], __fmul_rn(e[i + j], e[i + j]));
        float X = __fadd_rn(__fadd_rn(r[0], r[1]), __fadd_rn(r[2], r[3]));
        float Y = __fadd_rn(__fadd_rn(r[4], r[5]), __fadd_rn(r[6], r[7]));
        se[t] = __fadd_rn(X, Y);
    }
}

__global__ __launch_bounds__(256, 2) void vq_main(const float* __restrict__ in,
                                                  const float* __restrict__ emb,
                                                  const float* __restrict__ se,
                                                  float* __restrict__ out,
                                                  double* __restrict__ loss_sum,
                                                  int* __restrict__ counts) {
    const int tid   = threadIdx.x;
    const int lane  = tid & 63;
    const int split = tid >> 6;
    const int n0    = blockIdx.x * PIXB;
    const int n     = n0 + lane;
    const int b     = n >> 12;          // batch
    const int s     = n & 4095;         // h*64+w within image
    const float* xp = in + ((size_t)b << 18) + s;

    // x for this pixel in registers (stride-4096 across d; coalesced across lanes)
    float x[D];
    #pragma unroll
    for (int d = 0; d < D; ++d) x[d] = xp[(size_t)d << 12];
    // Pin x[] into VGPRs: make each element an asm def so the backend cannot
    // rematerialize the global loads inside the k-loop (round-3: VGPR=48 ->
    // x reloaded through L1 every iteration, VALUBusy 59%).
    #pragma unroll
    for (int d = 0; d < D; ++d) asm volatile("" : "+v"(x[d]));

    // s_x exactly as numpy's pairwise_sum(flat*flat) for n=64
    float sx;
    {
        float r[8];
        #pragma unroll
        for (int j = 0; j < 8; ++j) r[j] = __fmul_rn(x[j], x[j]);
        #pragma unroll
        for (int i = 8; i < D; i += 8)
            #pragma unroll
            for (int j = 0; j < 8; ++j)
                r[j] = __fadd_rn(r[j], __fmul_rn(x[i + j], x[i + j]));
        float X = __fadd_rn(__fadd_rn(r[0], r[1]), __fadd_rn(r[2], r[3]));
        float Y = __fadd_rn(__fadd_rn(r[4], r[5]), __fadd_rn(r[6], r[7]));
        sx = __fadd_rn(X, Y);
    }

    // wave-uniform codebook chunk base -> scalar loads for emb/se
    const int kbase = __builtin_amdgcn_readfirstlane(split * KCHUNK);
    const float* eb = emb + (size_t)kbase * D;
    const float* hb = se + kbase;

    float best = 3.0e38f;
    int bestk  = 0x7fffffff;

    for (int k = 0; k < KCHUNK; k += 4) {
        const float* e0 = eb + (size_t)(k + 0) * D;
        const float* e1 = eb + (size_t)(k + 1) * D;
        const float* e2 = eb + (size_t)(k + 2) * D;
        const float* e3 = eb + (size_t)(k + 3) * D;
        // sgemm-style dot: single sequential fused-FMA chain over d, per code
        float a0 = 0.f, a1 = 0.f, a2 = 0.f, a3 = 0.f;
        #pragma unroll
        for (int d = 0; d < D; ++d) {
            a0 = fmaf(x[d], e0[d], a0);
            a1 = fmaf(x[d], e1[d], a1);
            a2 = fmaf(x[d], e2[d], a2);
            a3 = fmaf(x[d], e3[d], a3);
        }
        // numpy: fl( fl(sx + se_k) - 2*m_k ), evaluated (A+B) - 2.0*M
        float s0 = __fsub_rn(__fadd_rn(sx, hb[k + 0]), __fmul_rn(2.0f, a0));
        float s1 = __fsub_rn(__fadd_rn(sx, hb[k + 1]), __fmul_rn(2.0f, a1));
        float s2 = __fsub_rn(__fadd_rn(sx, hb[k + 2]), __fmul_rn(2.0f, a2));
        float s3 = __fsub_rn(__fadd_rn(sx, hb[k + 3]), __fmul_rn(2.0f, a3));
        // strict < in ascending k == np.argmin first-min semantics
        if (s0 < best) { best = s0; bestk = kbase + k + 0; }
        if (s1 < best) { best = s1; bestk = kbase + k + 1; }
        if (s2 < best) { best = s2; bestk = kbase + k + 2; }
        if (s3 < best) { best = s3; bestk = kbase + k + 3; }
    }

    __shared__ float sb[SPLIT][PIXB];
    __shared__ int   sk[SPLIT][PIXB];
    __shared__ int   skfin[PIXB];
    sb[split][lane] = best;
    sk[split][lane] = bestk;
    __syncthreads();

    if (split == 0) {
        // ascending split order + strict < preserves np.argmin first-min
        #pragma unroll
        for (int j = 1; j < SPLIT; ++j) {
            float bj = sb[j][lane];
            int   kj = sk[j][lane];
            if (bj < best) { best = bj; bestk = kj; }
        }
        skfin[lane] = bestk;
        atomicAdd(&counts[bestk], 1);
        out[IDX_OFF + (unsigned)n] = (float)bestk;

        // quantized (NCHW) + per-pixel squared error
        const float* eq = emb + (size_t)bestk * D;
        float* qout = out + QUANT_OFF + ((size_t)b << 18) + s;
        float mse = 0.f;
        #pragma unroll
        for (int d = 0; d < D; ++d) {
            float q = eq[d];
            qout[(size_t)d << 12] = q;
            float df = q - x[d];
            mse = fmaf(df, df, mse);
        }
        #pragma unroll
        for (int off = 32; off; off >>= 1) mse += __shfl_down(mse, off);
        if (lane == 0) atomicAdd(loss_sum, (double)mse);
    }
    __syncthreads();

    // one-hot encodings rows for this block's 64 pixels (256 KB).
    // Region starts at ENC_OFF + n0*1024 (global float idx == 2 mod 4), so
    // shift by 2 floats for aligned float4 stores; head/tail as float2.
    float4* dst4 = (float4*)(out + ENC_OFF + (size_t)n0 * KCODES + 2);
    for (int i = tid; i < 16383; i += BLOCK) {
        int flat = (i << 2) + 2;          // 2 .. 65530
        int r0 = flat >> 10;
        int r1 = (flat + 3) >> 10;        // row crossing only at c==1022
        int k0 = skfin[r0];
        int k1 = skfin[r1];
        int c  = flat & 1023;             // in {2,6,...,1022}
        float4 v;
        v.x = (c == k0) ? 1.f : 0.f;
        v.y = (c + 1 == k0) ? 1.f : 0.f;
        v.z = (((flat + 2) & 1023) == k1) ? 1.f : 0.f;
        v.w = (((flat + 3) & 1023) == k1) ? 1.f : 0.f;
        dst4[i] = v;
    }
    if (tid == 0) {
        float2* dh = (float2*)(out + ENC_OFF + (size_t)n0 * KCODES);
        int kh = skfin[0];
        float2 h2; h2.x = (kh == 0) ? 1.f : 0.f; h2.y = (kh == 1) ? 1.f : 0.f;
        *dh = h2;
        float2* dt = (float2*)(out + ENC_OFF + (size_t)n0 * KCODES + 65534);
        int kt = skfin[63];
        float2 t2; t2.x = (kt == 1022) ? 1.f : 0.f; t2.y = (kt == 1023) ? 1.f : 0.f;
        *dt = t2;
    }
}

__global__ __launch_bounds__(256) void vq_fin(const double* __restrict__ loss_sum,
                                              const int* __restrict__ counts,
                                              float* __restrict__ out) {
    __shared__ double red[256];
    int t = threadIdx.x;
    double ent = 0.0;
    for (int k = t; k < KCODES; k += 256) {
        double p = (double)counts[k] / 65536.0;
        ent -= p * log(p + 1e-10);
    }
    red[t] = ent;
    __syncthreads();
    for (int o = 128; o; o >>= 1) {
        if (t < o) red[t] += red[t + o];
        __syncthreads();
    }
    if (t == 0) {
        out[PERP_OFF] = (float)exp(red[0]);
        out[0] = (float)(1.25 * (*loss_sum) / 4194304.0);
    }
}

extern "C" void kernel_launch(void* const* d_in, const int* in_sizes, int n_in,
                              void* d_out, int out_size, void* d_ws, size_t ws_size,
                              hipStream_t stream) {
    const float* in  = (const float*)d_in[0];
    const float* emb = (const float*)d_in[1];
    float* out = (float*)d_out;

    double* loss_sum = (double*)d_ws;
    int*    counts   = (int*)((char*)d_ws + 8);
    float*  se       = (float*)((char*)d_ws + 8 + 4096);

    vq_init<<<4, 256, 0, stream>>>(emb, loss_sum, counts, se);
    vq_main<<<NPIX / PIXB, BLOCK, 0, stream>>>(in, emb, se, out, loss_sum, counts);
    vq_fin<<<1, 256, 0, stream>>>(loss_sum, counts, out);
}

// Round 5
// 199.007 us; speedup vs baseline: 1.3082x; 1.3082x over previous
//
#include <hip/hip_runtime.h>

#define NPIX    65536
#define D       64
#define KCODES  1024
#define SPLIT   4
#define KCHUNK  (KCODES / SPLIT)   // 256
#define PIXB    64
#define BLOCK   256

// d_out layout (floats):
//   [0]                  loss
//   [1 .. 4194305)       quantized_out (NCHW, 16x64x64x64)
//   [4194305]            perplexity
//   [4194306 .. 71303170) encodings (65536 x 1024)
//   [71303170 .. 71368706) indices (as float)
#define QUANT_OFF 1
#define PERP_OFF  4194305
#define ENC_OFF   4194306u
#define IDX_OFF   71303170u

// numpy pairwise_sum (8 <= n <= 128) for n=64: 8 accumulators over stride-8
// lanes, sequential adds, then ((r0+r1)+(r2+r3))+((r4+r5)+(r6+r7)).
// All ops via __fmul_rn/__fadd_rn so the compiler cannot contract or reorder.

__global__ __launch_bounds__(256) void vq_init(const float* __restrict__ emb,
                                               double* __restrict__ loss_sum,
                                               int* __restrict__ counts,
                                               float* __restrict__ se) {
    int t = blockIdx.x * 256 + threadIdx.x;
    if (t == 0) *loss_sum = 0.0;
    if (t < KCODES) {
        counts[t] = 0;
        const float* e = emb + (size_t)t * D;
        float r[8];
        #pragma unroll
        for (int j = 0; j < 8; ++j) r[j] = __fmul_rn(e[j], e[j]);
        #pragma unroll
        for (int i = 8; i < D; i += 8)
            #pragma unroll
            for (int j = 0; j < 8; ++j)
                r[j] = __fadd_rn(r[j], __fmul_rn(e[i + j], e[i + j]));
        float X = __fadd_rn(__fadd_rn(r[0], r[1]), __fadd_rn(r[2], r[3]));
        float Y = __fadd_rn(__fadd_rn(r[4], r[5]), __fadd_rn(r[6], r[7]));
        se[t] = __fadd_rn(X, Y);
    }
}

// waves_per_eu(4,4): pin the allocator's occupancy target to 4 waves/EU
// (= our grid's delivered occupancy) so the VGPR budget is 128 and x[64]
// stays register-resident. Rounds 3/4: default target (8/EU, 64 VGPR) forced
// remat-from-global / scratch-spill of x -> VALUBusy 59-63%, 243-271 us.
__global__ __attribute__((amdgpu_flat_work_group_size(256, 256),
                          amdgpu_waves_per_eu(4, 4)))
void vq_main(const float* __restrict__ in,
             const float* __restrict__ emb,
             const float* __restrict__ se,
             float* __restrict__ out,
             double* __restrict__ loss_sum,
             int* __restrict__ counts) {
    const int tid   = threadIdx.x;
    const int lane  = tid & 63;
    const int split = tid >> 6;
    const int n0    = blockIdx.x * PIXB;
    const int n     = n0 + lane;
    const int b     = n >> 12;          // batch
    const int s     = n & 4095;         // h*64+w within image
    const float* xp = in + ((size_t)b << 18) + s;

    // x for this pixel in registers (stride-4096 across d; coalesced across lanes)
    float x[D];
    #pragma unroll
    for (int d = 0; d < D; ++d) x[d] = xp[(size_t)d << 12];
    // keep x as asm defs so the backend cannot sink the loads into the k-loop
    #pragma unroll
    for (int d = 0; d < D; ++d) asm volatile("" : "+v"(x[d]));

    // s_x exactly as numpy's pairwise_sum(flat*flat) for n=64
    float sx;
    {
        float r[8];
        #pragma unroll
        for (int j = 0; j < 8; ++j) r[j] = __fmul_rn(x[j], x[j]);
        #pragma unroll
        for (int i = 8; i < D; i += 8)
            #pragma unroll
            for (int j = 0; j < 8; ++j)
                r[j] = __fadd_rn(r[j], __fmul_rn(x[i + j], x[i + j]));
        float X = __fadd_rn(__fadd_rn(r[0], r[1]), __fadd_rn(r[2], r[3]));
        float Y = __fadd_rn(__fadd_rn(r[4], r[5]), __fadd_rn(r[6], r[7]));
        sx = __fadd_rn(X, Y);
    }

    // wave-uniform codebook chunk base -> scalar (s_load) codebook reads
    const int kbase = __builtin_amdgcn_readfirstlane(split * KCHUNK);
    const float* eb = emb + (size_t)kbase * D;
    const float* hb = se + kbase;

    float best = 3.0e38f;
    int bestk  = 0x7fffffff;

    for (int k = 0; k < KCHUNK; k += 4) {
        const float* e0 = eb + (size_t)(k + 0) * D;
        const float* e1 = eb + (size_t)(k + 1) * D;
        const float* e2 = eb + (size_t)(k + 2) * D;
        const float* e3 = eb + (size_t)(k + 3) * D;
        // sgemm-style dot: single sequential fused-FMA chain over d, per code
        float a0 = 0.f, a1 = 0.f, a2 = 0.f, a3 = 0.f;
        #pragma unroll
        for (int d = 0; d < D; ++d) {
            a0 = fmaf(x[d], e0[d], a0);
            a1 = fmaf(x[d], e1[d], a1);
            a2 = fmaf(x[d], e2[d], a2);
            a3 = fmaf(x[d], e3[d], a3);
        }
        // numpy: fl( fl(sx + se_k) - 2*m_k ), evaluated (A+B) - 2.0*M
        float s0 = __fsub_rn(__fadd_rn(sx, hb[k + 0]), __fmul_rn(2.0f, a0));
        float s1 = __fsub_rn(__fadd_rn(sx, hb[k + 1]), __fmul_rn(2.0f, a1));
        float s2 = __fsub_rn(__fadd_rn(sx, hb[k + 2]), __fmul_rn(2.0f, a2));
        float s3 = __fsub_rn(__fadd_rn(sx, hb[k + 3]), __fmul_rn(2.0f, a3));
        // strict < in ascending k == np.argmin first-min semantics
        if (s0 < best) { best = s0; bestk = kbase + k + 0; }
        if (s1 < best) { best = s1; bestk = kbase + k + 1; }
        if (s2 < best) { best = s2; bestk = kbase + k + 2; }
        if (s3 < best) { best = s3; bestk = kbase + k + 3; }
    }

    __shared__ float sb[SPLIT][PIXB];
    __shared__ int   sk[SPLIT][PIXB];
    __shared__ int   skfin[PIXB];
    sb[split][lane] = best;
    sk[split][lane] = bestk;
    __syncthreads();

    if (split == 0) {
        // ascending split order + strict < preserves np.argmin first-min
        #pragma unroll
        for (int j = 1; j < SPLIT; ++j) {
            float bj = sb[j][lane];
            int   kj = sk[j][lane];
            if (bj < best) { best = bj; bestk = kj; }
        }
        skfin[lane] = bestk;
        atomicAdd(&counts[bestk], 1);
        out[IDX_OFF + (unsigned)n] = (float)bestk;

        // quantized (NCHW) + per-pixel squared error
        const float* eq = emb + (size_t)bestk * D;
        float* qout = out + QUANT_OFF + ((size_t)b << 18) + s;
        float mse = 0.f;
        #pragma unroll
        for (int d = 0; d < D; ++d) {
            float q = eq[d];
            qout[(size_t)d << 12] = q;
            float df = q - x[d];
            mse = fmaf(df, df, mse);
        }
        #pragma unroll
        for (int off = 32; off; off >>= 1) mse += __shfl_down(mse, off);
        if (lane == 0) atomicAdd(loss_sum, (double)mse);
    }
    __syncthreads();

    // one-hot encodings rows for this block's 64 pixels (256 KB).
    // Region starts at ENC_OFF + n0*1024 (global float idx == 2 mod 4), so
    // shift by 2 floats for aligned float4 stores; head/tail as float2.
    float4* dst4 = (float4*)(out + ENC_OFF + (size_t)n0 * KCODES + 2);
    for (int i = tid; i < 16383; i += BLOCK) {
        int flat = (i << 2) + 2;          // 2 .. 65530
        int r0 = flat >> 10;
        int r1 = (flat + 3) >> 10;        // row crossing only at c==1022
        int k0 = skfin[r0];
        int k1 = skfin[r1];
        int c  = flat & 1023;             // in {2,6,...,1022}
        float4 v;
        v.x = (c == k0) ? 1.f : 0.f;
        v.y = (c + 1 == k0) ? 1.f : 0.f;
        v.z = (((flat + 2) & 1023) == k1) ? 1.f : 0.f;
        v.w = (((flat + 3) & 1023) == k1) ? 1.f : 0.f;
        dst4[i] = v;
    }
    if (tid == 0) {
        float2* dh = (float2*)(out + ENC_OFF + (size_t)n0 * KCODES);
        int kh = skfin[0];
        float2 h2; h2.x = (kh == 0) ? 1.f : 0.f; h2.y = (kh == 1) ? 1.f : 0.f;
        *dh = h2;
        float2* dt = (float2*)(out + ENC_OFF + (size_t)n0 * KCODES + 65534);
        int kt = skfin[63];
        float2 t2; t2.x = (kt == 1022) ? 1.f : 0.f; t2.y = (kt == 1023) ? 1.f : 0.f;
        *dt = t2;
    }
}

__global__ __launch_bounds__(256) void vq_fin(const double* __restrict__ loss_sum,
                                              const int* __restrict__ counts,
                                              float* __restrict__ out) {
    __shared__ double red[256];
    int t = threadIdx.x;
    double ent = 0.0;
    for (int k = t; k < KCODES; k += 256) {
        double p = (double)counts[k] / 65536.0;
        ent -= p * log(p + 1e-10);
    }
    red[t] = ent;
    __syncthreads();
    for (int o = 128; o; o >>= 1) {
        if (t < o) red[t] += red[t + o];
        __syncthreads();
    }
    if (t == 0) {
        out[PERP_OFF] = (float)exp(red[0]);
        out[0] = (float)(1.25 * (*loss_sum) / 4194304.0);
    }
}

extern "C" void kernel_launch(void* const* d_in, const int* in_sizes, int n_in,
                              void* d_out, int out_size, void* d_ws, size_t ws_size,
                              hipStream_t stream) {
    const float* in  = (const float*)d_in[0];
    const float* emb = (const float*)d_in[1];
    float* out = (float*)d_out;

    double* loss_sum = (double*)d_ws;
    int*    counts   = (int*)((char*)d_ws + 8);
    float*  se       = (float*)((char*)d_ws + 8 + 4096);

    vq_init<<<4, 256, 0, stream>>>(emb, loss_sum, counts, se);
    vq_main<<<NPIX / PIXB, BLOCK, 0, stream>>>(in, emb, se, out, loss_sum, counts);
    vq_fin<<<1, 256, 0, stream>>>(loss_sum, counts, out);
}